// Round 5
// baseline (382.432 us; speedup 1.0000x reference)
//
#include <hip/hip_runtime.h>

// Fused NNUE (HalfKA) forward for MI355X — v4: one position per WAVE.
//
// - int8 table in ws (EXACT: fake_quant(ftw,16)=rint, |values|<=~35; proven
//   absmax 0.0 in R2-R4).
// - Wave-per-position: zero __syncthreads, zero LDS. Lane l owns cols
//   16l..16l+15 of both sides (packed i16 accumulators, |sum|<=32*35+bias,
//   exact). Feature indices: one per lane, broadcast via v_readlane (literal
//   lane) -> gather loads are saddr + const voffset (no VALU addressing).
// - Pairwise: xor-32 lane exchange (ds_bpermute). Products fit u16 (<=16129),
//   scaled by 2^-7 (exact) before fc0 -> identical float classes to reference.
// - fc0 weights pre-quantized AND pre-permuted (x,z,y,w per 4) to match the
//   even/odd i16 unpack order; ft bias pre-packed to i16. fc1/fc2 pre-quant.

#define NFEATS 32
#define TBL_BYTES  (45056u * 1024u)          // 46,137,344
#define TBL_N4     11534336
#define TBL_G8     (TBL_N4 / 8)              // 1,441,792
#define W0_CHUNKS  (8 * 16 * 64)             // 8192 (16-float chunks)
#define FC1_N4     2048
#define FC2_N4     64
#define BIAS_CHUNKS 64
#define OFF_W0   ((size_t)TBL_BYTES)
#define OFF_W1   (OFF_W0 + (size_t)8 * 16 * 1024 * 4)    // +524288
#define OFF_W2   (OFF_W1 + (size_t)8 * 32 * 32 * 4)      // +32768
#define OFF_BI   (OFF_W2 + (size_t)8 * 32 * 4)           // +1024
#define WS_NEED  (OFF_BI + 2048)

typedef short v2s __attribute__((ext_vector_type(2)));

__device__ __forceinline__ float q16f(float x) {
    float r = rintf(x);
    return fminf(fmaxf(r, -32768.f), 32767.f);
}
__device__ __forceinline__ float q8f(float x) {
    float r = rintf(x);
    return fminf(fmaxf(r, -128.f), 127.f);
}
__device__ __forceinline__ float4 q8f4(float4 v) {
    return make_float4(q8f(v.x), q8f(v.y), q8f(v.z), q8f(v.w));
}
__device__ __forceinline__ float clip127(float x) {
    return fminf(fmaxf(x, 0.f), 127.f);
}
// sign-extended packed pairs from 4 packed int8 [b0,b1,b2,b3]:
// sx_even -> (sext b0, sext b2), sx_odd -> (sext b1, sext b3)
__device__ __forceinline__ v2s sx_even(int p) {
    union { int i; v2s s; } u; u.i = p << 8; u.s = u.s >> 8; return u.s;
}
__device__ __forceinline__ v2s sx_odd(int p) {
    union { int i; v2s s; } u; u.i = p; u.s = u.s >> 8; return u.s;
}
__device__ __forceinline__ void acc8(v2s a[8], int4 p) {
    a[0] += sx_even(p.x); a[1] += sx_odd(p.x);
    a[2] += sx_even(p.y); a[3] += sx_odd(p.y);
    a[4] += sx_even(p.z); a[5] += sx_odd(p.z);
    a[6] += sx_even(p.w); a[7] += sx_odd(p.w);
}
__device__ __forceinline__ v2s clip_pk(v2s v) {
    v2s r;
    r.x = v.x < 0 ? 0 : (v.x > 127 ? (short)127 : v.x);
    r.y = v.y < 0 ? 0 : (v.y > 127 ? (short)127 : v.y);
    return r;
}
__device__ __forceinline__ int v2s_as_int(v2s v) {
    union { v2s s; int i; } u; u.s = v; return u.i;
}
__device__ __forceinline__ v2s int_as_v2s(int v) {
    union { int i; v2s s; } u; u.i = v; return u.s;
}

// ---------------- pass 1: table + packed/permuted weights -----------------
__device__ __forceinline__ int pack4i8(float4 v) {
    const int a = (int)rintf(fminf(fmaxf(v.x, -127.f), 127.f));
    const int b = (int)rintf(fminf(fmaxf(v.y, -127.f), 127.f));
    const int c = (int)rintf(fminf(fmaxf(v.z, -127.f), 127.f));
    const int d = (int)rintf(fminf(fmaxf(v.w, -127.f), 127.f));
    return (a & 0xff) | ((b & 0xff) << 8) | ((c & 0xff) << 16) | (d << 24);
}

__global__ __launch_bounds__(256) void cvt_v4(
    const float4* __restrict__ tbl, const float* __restrict__ fc0,
    const float4* __restrict__ fc1, const float4* __restrict__ fc2,
    const float* __restrict__ ft_bias, char* __restrict__ ws)
{
    const int i = blockIdx.x * 256 + threadIdx.x;
    if (i < TBL_G8) {
        const float4* p = tbl + (size_t)i * 8;
        int4 a, b;
        a.x = pack4i8(p[0]); a.y = pack4i8(p[1]);
        a.z = pack4i8(p[2]); a.w = pack4i8(p[3]);
        b.x = pack4i8(p[4]); b.y = pack4i8(p[5]);
        b.z = pack4i8(p[6]); b.w = pack4i8(p[7]);
        int4* o = (int4*)ws;
        o[2 * (size_t)i]     = a;
        o[2 * (size_t)i + 1] = b;
        return;
    }
    int j = i - TBL_G8;
    if (j < W0_CHUNKS) {
        // fc0 chunk j = ((bk*16+o)*64 + lane): quantize + permute (x,z,y,w)
        const float4* s = (const float4*)(fc0 + (size_t)j * 16);
        const float4 a = q8f4(s[0]), b = q8f4(s[1]),
                     c = q8f4(s[2]), d = q8f4(s[3]);
        float4* o = (float4*)(ws + OFF_W0 + (size_t)j * 64);
        o[0] = make_float4(a.x, a.z, a.y, a.w);
        o[1] = make_float4(b.x, b.z, b.y, b.w);
        o[2] = make_float4(c.x, c.z, c.y, c.w);
        o[3] = make_float4(d.x, d.z, d.y, d.w);
        return;
    }
    j -= W0_CHUNKS;
    if (j < FC1_N4) { ((float4*)(ws + OFF_W1))[j] = q8f4(fc1[j]); return; }
    j -= FC1_N4;
    if (j < FC2_N4) { ((float4*)(ws + OFF_W2))[j] = q8f4(fc2[j]); return; }
    j -= FC2_N4;
    if (j < BIAS_CHUNKS) {
        // bias cols 16j..16j+15 -> i16, permuted (c0,c2,c1,c3) per 4-group
        const float* s = ft_bias + j * 16;
        short tmp[16];
        #pragma unroll
        for (int g = 0; g < 4; ++g) {
            tmp[4 * g + 0] = (short)q16f(s[4 * g + 0]);
            tmp[4 * g + 1] = (short)q16f(s[4 * g + 2]);
            tmp[4 * g + 2] = (short)q16f(s[4 * g + 1]);
            tmp[4 * g + 3] = (short)q16f(s[4 * g + 3]);
        }
        int4* o = (int4*)(ws + OFF_BI + (size_t)j * 32);
        o[0] = *(const int4*)&tmp[0];
        o[1] = *(const int4*)&tmp[8];
    }
}

// ---------------- pass 2: wave-per-position fused network -----------------
__global__ __launch_bounds__(256, 4) void nnue_v4(
    const int* __restrict__ w_feats, const int* __restrict__ w_offsets,
    const int* __restrict__ b_feats, const int* __restrict__ b_offsets,
    const int* __restrict__ stm_arr, const int* __restrict__ bucket_arr,
    const char* __restrict__ tbl,   const float* __restrict__ w0q,
    const float* __restrict__ w1q,  const float* __restrict__ w2q,
    const char* __restrict__ biasI, const float* __restrict__ psqt_weight,
    const float* __restrict__ fc0_b, const float* __restrict__ fc1_b,
    const float* __restrict__ fc2_b,
    float* __restrict__ out, int n_wf, int n_bf, int nb)
{
    const int t = threadIdx.x;
    const int l = t & 63;
    const int wv = t >> 6;
    const int p = blockIdx.x * 4 + wv;
    if (p >= nb) return;

    const int fs = w_offsets[p];
    const int fe = (p + 1 < nb) ? w_offsets[p + 1] : n_wf;
    const int gs = b_offsets[p];
    const int ge = (p + 1 < nb) ? b_offsets[p + 1] : n_bf;
    const int cw = min(fe - fs, NFEATS);
    const int cb = min(ge - gs, NFEATS);

    const int k32 = l & 31;
    int myidx = 0;
    if (l < 32) { if (k32 < cw) myidx = w_feats[fs + k32]; }
    else        { if (k32 < cb) myidx = b_feats[gs + k32]; }

    const int stm = stm_arr[p];
    const int bk  = bucket_arr[p];

    // ---- gather: lane l owns cols 16l..16l+15 of both sides --------------
    v2s aw[8] = {{0,0},{0,0},{0,0},{0,0},{0,0},{0,0},{0,0},{0,0}};
    v2s ab[8] = {{0,0},{0,0},{0,0},{0,0},{0,0},{0,0},{0,0},{0,0}};

    if (cw == NFEATS && cb == NFEATS) {
        #pragma unroll
        for (int k = 0; k < NFEATS; ++k) {
            const int rw = __builtin_amdgcn_readlane(myidx, k);
            const int rb = __builtin_amdgcn_readlane(myidx, 32 + k);
            const int4 pw = ((const int4*)(tbl + ((size_t)rw << 10)))[l];
            const int4 pb = ((const int4*)(tbl + ((size_t)rb << 10)))[l];
            acc8(aw, pw);
            acc8(ab, pb);
        }
    } else {
        #pragma unroll
        for (int k = 0; k < NFEATS; ++k) {
            if (k < cw) {
                const int rw = __builtin_amdgcn_readlane(myidx, k);
                acc8(aw, ((const int4*)(tbl + ((size_t)rw << 10)))[l]);
            }
            if (k < cb) {
                const int rb = __builtin_amdgcn_readlane(myidx, 32 + k);
                acc8(ab, ((const int4*)(tbl + ((size_t)rb << 10)))[l]);
            }
        }
    }

    // ---- bias add (exact in i16) ------------------------------------------
    {
        union { int4 q[2]; v2s s[8]; } bb;
        bb.q[0] = ((const int4*)biasI)[2 * l];
        bb.q[1] = ((const int4*)biasI)[2 * l + 1];
        #pragma unroll
        for (int i = 0; i < 8; ++i) { aw[i] += bb.s[i]; ab[i] += bb.s[i]; }
    }

    // ---- stm select + xor-32 exchange + pairwise product -----------------
    // lanes<32 keep stm-side (lo cols), receive partner's stm-side (hi cols);
    // lanes>=32 keep opp-side (hi cols), receive partner's opp-side (lo).
    float ftf[16];   // ft values for cols 16l..16l+15, scaled by 2^-7 (exact)
    {
        const bool low = (l < 32);
        #pragma unroll
        for (int i = 0; i < 8; ++i) {
            const v2s sv = stm ? ab[i] : aw[i];
            const v2s ov = stm ? aw[i] : ab[i];
            const v2s own  = low ? sv : ov;
            const int send = v2s_as_int(low ? ov : sv);
            const v2s rcv  = int_as_v2s(__shfl_xor(send, 32));
            const v2s a = clip_pk(own);
            const v2s b = clip_pk(rcv);
            ftf[2 * i]     = (float)(a.x * b.x) * 0.0078125f;
            ftf[2 * i + 1] = (float)(a.y * b.y) * 0.0078125f;
        }
    }

    // ---- fc0: 16 partial dots, butterfly reduce ---------------------------
    float s0[16];
    {
        const float4* w0p = (const float4*)(w0q + (size_t)bk * 16 * 1024);
        #pragma unroll
        for (int o = 0; o < 16; ++o) {
            const float4* wr = w0p + o * 256 + l * 4;
            const float4 A = wr[0], B = wr[1], C = wr[2], D = wr[3];
            s0[o] = ftf[0]  * A.x + ftf[1]  * A.y + ftf[2]  * A.z + ftf[3]  * A.w
                  + ftf[4]  * B.x + ftf[5]  * B.y + ftf[6]  * B.z + ftf[7]  * B.w
                  + ftf[8]  * C.x + ftf[9]  * C.y + ftf[10] * C.z + ftf[11] * C.w
                  + ftf[12] * D.x + ftf[13] * D.y + ftf[14] * D.z + ftf[15] * D.w;
        }
        #pragma unroll
        for (int o = 0; o < 16; ++o) {
            float v = s0[o];
            v += __shfl_xor(v, 32);
            v += __shfl_xor(v, 16);
            v += __shfl_xor(v,  8);
            v += __shfl_xor(v,  4);
            v += __shfl_xor(v,  2);
            v += __shfl_xor(v,  1);
            s0[o] = v;
        }
    }

    // ---- o0 + slab --------------------------------------------------------
    float o0v[16];
    {
        const float* b0 = fc0_b + bk * 16;
        #pragma unroll
        for (int o = 0; o < 16; ++o) o0v[o] = s0[o] + rintf(b0[o]);
    }
    float sqr[15], rel[15];
    #pragma unroll
    for (int i = 0; i < 15; ++i) {
        sqr[i] = clip127(o0v[i] * o0v[i] * (1.f / 524288.f));
        rel[i] = clip127(o0v[i] * 0.015625f);
    }

    // ---- fc1 (lane j = l&31 computes output j) ----------------------------
    float ac1v;
    {
        const int j = l & 31;
        const float4* w1r = (const float4*)(w1q + ((size_t)bk * 32 + j) * 32);
        const float4 W0 = w1r[0], W1 = w1r[1], W2 = w1r[2], W3 = w1r[3];
        const float4 W4 = w1r[4], W5 = w1r[5], W6 = w1r[6], W7 = w1r[7];
        float a1 = rintf(fc1_b[bk * 32 + j]);
        a1 += sqr[0]  * W0.x + sqr[1]  * W0.y + sqr[2]  * W0.z + sqr[3]  * W0.w
            + sqr[4]  * W1.x + sqr[5]  * W1.y + sqr[6]  * W1.z + sqr[7]  * W1.w
            + sqr[8]  * W2.x + sqr[9]  * W2.y + sqr[10] * W2.z + sqr[11] * W2.w
            + sqr[12] * W3.x + sqr[13] * W3.y + sqr[14] * W3.z + rel[0]  * W3.w
            + rel[1]  * W4.x + rel[2]  * W4.y + rel[3]  * W4.z + rel[4]  * W4.w
            + rel[5]  * W5.x + rel[6]  * W5.y + rel[7]  * W5.z + rel[8]  * W5.w
            + rel[9]  * W6.x + rel[10] * W6.y + rel[11] * W6.z + rel[12] * W6.w
            + rel[13] * W7.x + rel[14] * W7.y;
        ac1v = clip127(a1 * 0.015625f);
    }

    // ---- fc2 partial + reduce ---------------------------------------------
    float pr2;
    {
        const float wv2 = w2q[bk * 32 + (l & 31)];
        pr2 = (l < 32) ? ac1v * wv2 : 0.f;
        pr2 += __shfl_xor(pr2, 32);
        pr2 += __shfl_xor(pr2, 16);
        pr2 += __shfl_xor(pr2,  8);
        pr2 += __shfl_xor(pr2,  4);
        pr2 += __shfl_xor(pr2,  2);
        pr2 += __shfl_xor(pr2,  1);
    }

    // ---- psqt: per-half butterfly then cross ------------------------------
    float pv = 0.f;
    {
        const bool valid = (l < 32) ? (k32 < cw) : (k32 < cb);
        if (valid) pv = rintf(psqt_weight[myidx * 8 + bk]);
        pv += __shfl_xor(pv,  1);
        pv += __shfl_xor(pv,  2);
        pv += __shfl_xor(pv,  4);
        pv += __shfl_xor(pv,  8);
        pv += __shfl_xor(pv, 16);
    }
    const float cross = __shfl_xor(pv, 32);

    if (l == 0) {
        const float o2   = pr2 + rintf(fc2_b[bk]);
        const float skip = o0v[15] * (float)(9600.0 / 8128.0);
        const float ps   = stm ? cross : pv;     // lane0: pv=white, cross=black
        const float po   = stm ? pv : cross;
        out[p] = (0.5f * (ps - po) + o2 + skip) * 0.0625f;
    }
}

// ---------------- fallback (no ws): fp32 block-per-position ----------------
__global__ __launch_bounds__(256) void nnue_fb(
    const int* __restrict__ w_feats, const int* __restrict__ w_offsets,
    const int* __restrict__ b_feats, const int* __restrict__ b_offsets,
    const int* __restrict__ stm_arr, const int* __restrict__ bucket_arr,
    const float* __restrict__ ft_weight, const float* __restrict__ ft_bias,
    const float* __restrict__ psqt_weight,
    const float* __restrict__ fc0_w, const float* __restrict__ fc0_b,
    const float* __restrict__ fc1_w, const float* __restrict__ fc1_b,
    const float* __restrict__ fc2_w, const float* __restrict__ fc2_b,
    float* __restrict__ out, int n_wf, int n_bf, int nb)
{
    const int b = blockIdx.x;
    const int t = threadIdx.x;
    const int l = t & 63;
    const int w = t >> 6;

    __shared__ int s_fw[NFEATS], s_fb[NFEATS];
    __shared__ __align__(16) float s_acc[2][1024];
    __shared__ __align__(16) float s_ft[1024];
    __shared__ float s_o0[16];
    __shared__ float s_slab[32];
    __shared__ float s_ac1[32];
    __shared__ float s_psqt[2];

    const int ws = w_offsets[b];
    const int we = (b + 1 < nb) ? w_offsets[b + 1] : n_wf;
    const int bs = b_offsets[b];
    const int be = (b + 1 < nb) ? b_offsets[b + 1] : n_bf;
    const int cw = min(we - ws, NFEATS);
    const int cb = min(be - bs, NFEATS);

    if (t < NFEATS) s_fw[t] = (t < cw) ? w_feats[ws + t] : 0;
    else if (t < 2 * NFEATS) {
        const int k = t - NFEATS;
        s_fb[k] = (k < cb) ? b_feats[bs + k] : 0;
    }
    __syncthreads();

    const int stm = stm_arr[b];
    const int bk  = bucket_arr[b];

    if (t < 64) {
        const int side = t >> 5;
        const int k = t & 31;
        const int cnt = side ? cb : cw;
        float v = 0.f;
        if (k < cnt) v = rintf(psqt_weight[(side ? s_fb[k] : s_fw[k]) * 8 + bk]);
        v += __shfl_down(v, 16, 32); v += __shfl_down(v, 8, 32);
        v += __shfl_down(v, 4, 32);  v += __shfl_down(v, 2, 32);
        v += __shfl_down(v, 1, 32);
        if (k == 0) s_psqt[side] = v;
    }

    const float4* ftw4 = reinterpret_cast<const float4*>(ft_weight);
    float4 aw = make_float4(0, 0, 0, 0), ab = make_float4(0, 0, 0, 0);
    for (int k = 0; k < cw; ++k) {
        const float4 v = ftw4[s_fw[k] * 256 + t];
        aw.x += rintf(v.x); aw.y += rintf(v.y);
        aw.z += rintf(v.z); aw.w += rintf(v.w);
    }
    for (int k = 0; k < cb; ++k) {
        const float4 u = ftw4[s_fb[k] * 256 + t];
        ab.x += rintf(u.x); ab.y += rintf(u.y);
        ab.z += rintf(u.z); ab.w += rintf(u.w);
    }
    const float4 bv = reinterpret_cast<const float4*>(ft_bias)[t];
    aw.x += q16f(bv.x); aw.y += q16f(bv.y); aw.z += q16f(bv.z); aw.w += q16f(bv.w);
    ab.x += q16f(bv.x); ab.y += q16f(bv.y); ab.z += q16f(bv.z); ab.w += q16f(bv.w);
    reinterpret_cast<float4*>(&s_acc[0][4 * t])[0] = aw;
    reinterpret_cast<float4*>(&s_acc[1][4 * t])[0] = ab;
    __syncthreads();

    {
        float4 lo, hi;
        if (t < 128) {
            const float* sp = s_acc[stm];
            lo = ((const float4*)sp)[t]; hi = ((const float4*)sp)[t + 128];
        } else {
            const float* sp = s_acc[1 - stm];
            lo = ((const float4*)sp)[t - 128]; hi = ((const float4*)sp)[t];
        }
        float4 r;
        r.x = clip127(lo.x) * clip127(hi.x) * 0.0078125f;
        r.y = clip127(lo.y) * clip127(hi.y) * 0.0078125f;
        r.z = clip127(lo.z) * clip127(hi.z) * 0.0078125f;
        r.w = clip127(lo.w) * clip127(hi.w) * 0.0078125f;
        ((float4*)s_ft)[t] = r;
    }
    __syncthreads();

    {
        const float4* ftf4 = (const float4*)s_ft;
        const float4 f0 = ftf4[l], f1 = ftf4[l + 64],
                     f2 = ftf4[l + 128], f3 = ftf4[l + 192];
        #pragma unroll
        for (int o = 0; o < 4; ++o) {
            const int orow = 4 * w + o;
            const float4* wr = (const float4*)fc0_w + ((size_t)bk * 16 + orow) * 256;
            const float4 w0 = q8f4(wr[l]), w1 = q8f4(wr[l + 64]),
                         w2 = q8f4(wr[l + 128]), w3 = q8f4(wr[l + 192]);
            float acc = f0.x * w0.x + f0.y * w0.y + f0.z * w0.z + f0.w * w0.w
                      + f1.x * w1.x + f1.y * w1.y + f1.z * w1.z + f1.w * w1.w
                      + f2.x * w2.x + f2.y * w2.y + f2.z * w2.z + f2.w * w2.w
                      + f3.x * w3.x + f3.y * w3.y + f3.z * w3.z + f3.w * w3.w;
            acc += __shfl_down(acc, 32); acc += __shfl_down(acc, 16);
            acc += __shfl_down(acc, 8);  acc += __shfl_down(acc, 4);
            acc += __shfl_down(acc, 2);  acc += __shfl_down(acc, 1);
            if (l == 0) s_o0[orow] = acc + rintf(fc0_b[bk * 16 + orow]);
        }
    }
    __syncthreads();

    if (t < 32) {
        float v;
        if (t < 15)      v = clip127(s_o0[t] * s_o0[t] * (1.f / 524288.f));
        else if (t < 30) v = clip127(s_o0[t - 15] * 0.015625f);
        else             v = 0.f;
        s_slab[t] = v;
    }
    __syncthreads();

    if (t < 32) {
        const float* w1 = fc1_w + (size_t)bk * 32 * 32 + t * 32;
        float acc = rintf(fc1_b[bk * 32 + t]);
        #pragma unroll
        for (int i = 0; i < 32; ++i) acc += s_slab[i] * q8f(w1[i]);
        s_ac1[t] = clip127(acc * 0.015625f);
    }
    __syncthreads();

    if (t == 0) {
        const float* w2 = fc2_w + (size_t)bk * 32;
        float acc = rintf(fc2_b[bk]);
        #pragma unroll
        for (int i = 0; i < 32; ++i) acc += s_ac1[i] * q8f(w2[i]);
        const float skip = s_o0[15] * (float)(9600.0 / 8128.0);
        const float ps = stm ? s_psqt[1] : s_psqt[0];
        const float po = stm ? s_psqt[0] : s_psqt[1];
        out[b] = (0.5f * (ps - po) + acc + skip) * 0.0625f;
    }
}

extern "C" void kernel_launch(void* const* d_in, const int* in_sizes, int n_in,
                              void* d_out, int out_size, void* d_ws, size_t ws_size,
                              hipStream_t stream) {
    const int*   w_feats   = (const int*)d_in[0];
    const int*   w_offsets = (const int*)d_in[1];
    const int*   b_feats   = (const int*)d_in[2];
    const int*   b_offsets = (const int*)d_in[3];
    const int*   stm       = (const int*)d_in[4];
    const int*   bucket    = (const int*)d_in[5];
    const float* ft_weight = (const float*)d_in[6];
    const float* ft_bias   = (const float*)d_in[7];
    const float* psqt_w    = (const float*)d_in[8];
    const float* fc0_w     = (const float*)d_in[9];
    const float* fc0_b     = (const float*)d_in[10];
    const float* fc1_w     = (const float*)d_in[11];
    const float* fc1_b     = (const float*)d_in[12];
    const float* fc2_w     = (const float*)d_in[13];
    const float* fc2_b     = (const float*)d_in[14];
    float*       out       = (float*)d_out;

    const int nb   = in_sizes[4];
    const int n_wf = in_sizes[0];
    const int n_bf = in_sizes[2];

    if (ws_size >= WS_NEED) {
        const int nthreads = TBL_G8 + W0_CHUNKS + FC1_N4 + FC2_N4 + BIAS_CHUNKS;
        cvt_v4<<<(nthreads + 255) / 256, 256, 0, stream>>>(
            (const float4*)ft_weight, fc0_w, (const float4*)fc1_w,
            (const float4*)fc2_w, ft_bias, (char*)d_ws);

        const char*  tbl  = (const char*)d_ws;
        const float* w0q  = (const float*)((char*)d_ws + OFF_W0);
        const float* w1q  = (const float*)((char*)d_ws + OFF_W1);
        const float* w2q  = (const float*)((char*)d_ws + OFF_W2);
        const char*  bi   = (const char*)d_ws + OFF_BI;

        nnue_v4<<<(nb + 3) / 4, 256, 0, stream>>>(
            w_feats, w_offsets, b_feats, b_offsets, stm, bucket,
            tbl, w0q, w1q, w2q, bi, psqt_w, fc0_b, fc1_b, fc2_b,
            out, n_wf, n_bf, nb);
    } else {
        nnue_fb<<<nb, 256, 0, stream>>>(
            w_feats, w_offsets, b_feats, b_offsets, stm, bucket,
            ft_weight, ft_bias, psqt_w,
            fc0_w, fc0_b, fc1_w, fc1_b, fc2_w, fc2_b,
            out, n_wf, n_bf, nb);
    }
}

// Round 6
// 359.366 us; speedup vs baseline: 1.0642x; 1.0642x over previous
//
#include <hip/hip_runtime.h>

// Fused NNUE (HalfKA) forward for MI355X — v5: pair-in-thread, 128thr/block.
//
// - int8 table in ws (EXACT: fake_quant(ftw,16)=rint, |v|<=~35; absmax 0.0
//   R2-R5). Gather: block = 1 position; threads 0..63 own stm-side cols
//   (8u..8u+7, 8u+512..8u+519), threads 64..127 own opp-side. Two int2 loads
//   per row (one addr calc, +512 const offset). Packed-i16 accumulate
//   (|sum|<=32*35, exact). Pairwise product computed IN-THREAD (no LDS
//   round-trip, no stm exchange).
// - fc0: 8 ftf/thread x 16 outs; register-halving butterfly (17 shuffles);
//   one barrier; whole tail in wave 0. LDS ~700B -> occupancy VGPR-bound.
// - fc0/fc1/fc2 weights pre-quantized to fp32 in ws. All fc0 dot terms are
//   multiples of 2^-7; sums stayed in the exact-f32 class every round.

#define NFEATS 32
#define TBL_BYTES  (45056u * 1024u)          // 46,137,344
#define TBL_N4     11534336
#define FC0_N4     32768
#define FC1_N4     2048
#define FC2_N4     64
#define OFF_W0   ((size_t)TBL_BYTES)
#define OFF_W1   (OFF_W0 + (size_t)FC0_N4 * 16)
#define OFF_W2   (OFF_W1 + (size_t)FC1_N4 * 16)
#define WS_NEED  (OFF_W2 + (size_t)FC2_N4 * 16)

typedef short v2s __attribute__((ext_vector_type(2)));

__device__ __forceinline__ float q16f(float x) {
    float r = rintf(x);
    return fminf(fmaxf(r, -32768.f), 32767.f);
}
__device__ __forceinline__ float q8f(float x) {
    float r = rintf(x);
    return fminf(fmaxf(r, -128.f), 127.f);
}
__device__ __forceinline__ float4 q8f4(float4 v) {
    return make_float4(q8f(v.x), q8f(v.y), q8f(v.z), q8f(v.w));
}
__device__ __forceinline__ float clip127(float x) {
    return fminf(fmaxf(x, 0.f), 127.f);
}
// sign-extended packed pairs from dword [b0,b1,b2,b3]:
// sx_even -> (sext b0, sext b2), sx_odd -> (sext b1, sext b3)
__device__ __forceinline__ v2s sx_even(int p) {
    union { int i; v2s s; } u; u.i = p << 8; u.s = u.s >> 8; return u.s;
}
__device__ __forceinline__ v2s sx_odd(int p) {
    union { int i; v2s s; } u; u.i = p; u.s = u.s >> 8; return u.s;
}

// ---------------- pass 1: int8 table + quantized fc weights ---------------
__device__ __forceinline__ int pack4i8(float4 v) {
    const int a = (int)rintf(fminf(fmaxf(v.x, -127.f), 127.f));
    const int b = (int)rintf(fminf(fmaxf(v.y, -127.f), 127.f));
    const int c = (int)rintf(fminf(fmaxf(v.z, -127.f), 127.f));
    const int d = (int)rintf(fminf(fmaxf(v.w, -127.f), 127.f));
    return (a & 0xff) | ((b & 0xff) << 8) | ((c & 0xff) << 16) | (d << 24);
}

__global__ __launch_bounds__(256) void cvt_v5(
    const float4* __restrict__ tbl, const float4* __restrict__ fc0,
    const float4* __restrict__ fc1, const float4* __restrict__ fc2,
    char* __restrict__ ws)
{
    const int i = blockIdx.x * 256 + threadIdx.x;
    if (i < TBL_N4) {                          // 16B/lane read, 4B write
        ((int*)ws)[i] = pack4i8(tbl[i]);
        return;
    }
    int j = i - TBL_N4;
    if (j < FC0_N4) { ((float4*)(ws + OFF_W0))[j] = q8f4(fc0[j]); return; }
    j -= FC0_N4;
    if (j < FC1_N4) { ((float4*)(ws + OFF_W1))[j] = q8f4(fc1[j]); return; }
    j -= FC1_N4;
    if (j < FC2_N4) { ((float4*)(ws + OFF_W2))[j] = q8f4(fc2[j]); }
}

// ---------------- pass 2: fused gather + network --------------------------
__global__ __launch_bounds__(128) void nnue_v5(
    const int* __restrict__ w_feats, const int* __restrict__ w_offsets,
    const int* __restrict__ b_feats, const int* __restrict__ b_offsets,
    const int* __restrict__ stm_arr, const int* __restrict__ bucket_arr,
    const char* __restrict__ tbl,   const float* __restrict__ w0q,
    const float* __restrict__ w1q,  const float* __restrict__ w2q,
    const float* __restrict__ ft_bias, const float* __restrict__ psqt_weight,
    const float* __restrict__ fc0_b, const float* __restrict__ fc1_b,
    const float* __restrict__ fc2_b,
    float* __restrict__ out, int n_wf, int n_bf, int nb)
{
    const int b = blockIdx.x;
    const int t = threadIdx.x;
    const int l = t & 63;
    const int grpB = t >> 6;        // 0: stm side (ft cols 0..511), 1: opp

    __shared__ int   s_fw[NFEATS], s_fb[NFEATS];
    __shared__ float s_red[2][16];
    __shared__ float s_psqt[2];

    const int fs = w_offsets[b];
    const int fe = (b + 1 < nb) ? w_offsets[b + 1] : n_wf;
    const int gs = b_offsets[b];
    const int ge = (b + 1 < nb) ? b_offsets[b + 1] : n_bf;
    const int cw = min(fe - fs, NFEATS);
    const int cb = min(ge - gs, NFEATS);

    if (t < 32)                    s_fw[t] = (t < cw) ? w_feats[fs + t] : 0;
    else if (t >= 64 && t < 96) {
        const int k = t - 64;
        s_fb[k] = (k < cb) ? b_feats[gs + k] : 0;
    }
    __syncthreads();

    const int stm = stm_arr[b];
    const int bk  = bucket_arr[b];

    // ---- PSQT: wave0 lanes 0..31 = white, wave1 lanes 0..31 = black ------
    if (l < 32) {
        const int cnt = grpB ? cb : cw;
        float v = 0.f;
        if (l < cnt) {
            const int f = grpB ? s_fb[l] : s_fw[l];
            v = rintf(psqt_weight[f * 8 + bk]);
        }
        v += __shfl_down(v, 16, 32);
        v += __shfl_down(v,  8, 32);
        v += __shfl_down(v,  4, 32);
        v += __shfl_down(v,  2, 32);
        v += __shfl_down(v,  1, 32);
        if (l == 0) s_psqt[grpB] = v;   // [0]=white sum, [1]=black sum
    }

    // ---- gather: my side's rows, cols 8l..8l+7 and +512 -------------------
    const int* rows = (grpB ^ stm) ? s_fb : s_fw;
    const int  cnt  = (grpB ^ stm) ? cb : cw;
    const char* cp  = tbl + 8 * l;

    v2s le0 = {0,0}, lo0 = {0,0}, le1 = {0,0}, lo1 = {0,0};
    v2s he0 = {0,0}, ho0 = {0,0}, he1 = {0,0}, ho1 = {0,0};

    if (cnt == NFEATS) {
        #pragma unroll 8
        for (int k = 0; k < NFEATS; ++k) {
            const char* rp = cp + ((size_t)rows[k] << 10);
            const int2 plo = *(const int2*)rp;
            const int2 phi = *(const int2*)(rp + 512);
            le0 += sx_even(plo.x); lo0 += sx_odd(plo.x);
            le1 += sx_even(plo.y); lo1 += sx_odd(plo.y);
            he0 += sx_even(phi.x); ho0 += sx_odd(phi.x);
            he1 += sx_even(phi.y); ho1 += sx_odd(phi.y);
        }
    } else {
        for (int k = 0; k < cnt; ++k) {
            const char* rp = cp + ((size_t)rows[k] << 10);
            const int2 plo = *(const int2*)rp;
            const int2 phi = *(const int2*)(rp + 512);
            le0 += sx_even(plo.x); lo0 += sx_odd(plo.x);
            le1 += sx_even(plo.y); lo1 += sx_odd(plo.y);
            he0 += sx_even(phi.x); ho0 += sx_odd(phi.x);
            he1 += sx_even(phi.y); ho1 += sx_odd(phi.y);
        }
    }

    // ---- bias + pairwise product (in-thread, exact) -----------------------
    float ftf[8];
    {
        const float4 bA = ((const float4*)(ft_bias + 8 * l))[0];
        const float4 bB = ((const float4*)(ft_bias + 8 * l))[1];
        const float4 cA = ((const float4*)(ft_bias + 8 * l + 512))[0];
        const float4 cB = ((const float4*)(ft_bias + 8 * l + 512))[1];
        float lo_f[8] = {
            (float)le0.x + q16f(bA.x), (float)lo0.x + q16f(bA.y),
            (float)le0.y + q16f(bA.z), (float)lo0.y + q16f(bA.w),
            (float)le1.x + q16f(bB.x), (float)lo1.x + q16f(bB.y),
            (float)le1.y + q16f(bB.z), (float)lo1.y + q16f(bB.w) };
        float hi_f[8] = {
            (float)he0.x + q16f(cA.x), (float)ho0.x + q16f(cA.y),
            (float)he0.y + q16f(cA.z), (float)ho0.y + q16f(cA.w),
            (float)he1.x + q16f(cB.x), (float)ho1.x + q16f(cB.y),
            (float)he1.y + q16f(cB.z), (float)ho1.y + q16f(cB.w) };
        #pragma unroll
        for (int j = 0; j < 8; ++j)
            ftf[j] = clip127(lo_f[j]) * clip127(hi_f[j]) * 0.0078125f;
    }

    // ---- fc0 partials: 16 outputs over my 8 ft cols -----------------------
    float v[16];
    {
        const int wcol = grpB * 512 + 8 * l;
        const float* w0r = w0q + (size_t)bk * 16 * 1024 + wcol;
        #pragma unroll
        for (int o = 0; o < 16; ++o) {
            const float4 A = ((const float4*)(w0r + o * 1024))[0];
            const float4 B = ((const float4*)(w0r + o * 1024))[1];
            v[o] = ftf[0] * A.x + ftf[1] * A.y + ftf[2] * A.z + ftf[3] * A.w
                 + ftf[4] * B.x + ftf[5] * B.y + ftf[6] * B.z + ftf[7] * B.w;
        }
    }

    // ---- register-halving butterfly reduce (17 shuffles) ------------------
    // After levels 1,2,4,8: lane l holds full-wave sum of output
    // o = bitrev4(l&15); then s_red[wave][o].
    {
        #pragma unroll
        for (int j = 0; j < 8; ++j) {
            const bool up = (l & 1);
            const float send = up ? v[j] : v[j + 8];
            const float r = __shfl_xor(send, 1);
            v[j] = (up ? v[j + 8] : v[j]) + r;
        }
        #pragma unroll
        for (int j = 0; j < 4; ++j) {
            const bool up = (l & 2);
            const float send = up ? v[j] : v[j + 4];
            const float r = __shfl_xor(send, 2);
            v[j] = (up ? v[j + 4] : v[j]) + r;
        }
        #pragma unroll
        for (int j = 0; j < 2; ++j) {
            const bool up = (l & 4);
            const float send = up ? v[j] : v[j + 2];
            const float r = __shfl_xor(send, 4);
            v[j] = (up ? v[j + 2] : v[j]) + r;
        }
        {
            const bool up = (l & 8);
            const float send = up ? v[0] : v[1];
            const float r = __shfl_xor(send, 8);
            v[0] = (up ? v[1] : v[0]) + r;
        }
        v[0] += __shfl_xor(v[0], 16);
        v[0] += __shfl_xor(v[0], 32);
        if (l < 16) {
            const int o = ((l & 1) << 3) | ((l & 2) << 1)
                        | ((l & 4) >> 1) | ((l & 8) >> 3);
            s_red[grpB][o] = v[0];
        }
    }
    __syncthreads();

    // ---- tail: entirely in wave 0 -----------------------------------------
    if (t < 64) {
        float o0v[16];
        {
            const float* b0 = fc0_b + bk * 16;
            #pragma unroll
            for (int o = 0; o < 16; ++o)
                o0v[o] = s_red[0][o] + s_red[1][o] + rintf(b0[o]);
        }
        float sqr[15], rel[15];
        #pragma unroll
        for (int i = 0; i < 15; ++i) {
            sqr[i] = clip127(o0v[i] * o0v[i] * (1.f / 524288.f));
            rel[i] = clip127(o0v[i] * 0.015625f);
        }

        // fc1: lane j = l&31 computes output j (lanes 32..63 duplicate)
        float ac1v;
        {
            const int j = l & 31;
            const float4* w1r = (const float4*)(w1q + ((size_t)bk * 32 + j) * 32);
            const float4 W0 = w1r[0], W1 = w1r[1], W2 = w1r[2], W3 = w1r[3];
            const float4 W4 = w1r[4], W5 = w1r[5], W6 = w1r[6], W7 = w1r[7];
            float a1 = rintf(fc1_b[bk * 32 + j]);
            a1 += sqr[0]  * W0.x + sqr[1]  * W0.y + sqr[2]  * W0.z + sqr[3]  * W0.w
                + sqr[4]  * W1.x + sqr[5]  * W1.y + sqr[6]  * W1.z + sqr[7]  * W1.w
                + sqr[8]  * W2.x + sqr[9]  * W2.y + sqr[10] * W2.z + sqr[11] * W2.w
                + sqr[12] * W3.x + sqr[13] * W3.y + sqr[14] * W3.z + rel[0]  * W3.w
                + rel[1]  * W4.x + rel[2]  * W4.y + rel[3]  * W4.z + rel[4]  * W4.w
                + rel[5]  * W5.x + rel[6]  * W5.y + rel[7]  * W5.z + rel[8]  * W5.w
                + rel[9]  * W6.x + rel[10] * W6.y + rel[11] * W6.z + rel[12] * W6.w
                + rel[13] * W7.x + rel[14] * W7.y;
            ac1v = clip127(a1 * 0.015625f);
        }

        // fc2: lanes 0..31 contribute, butterfly reduce
        float pr2 = (l < 32) ? ac1v * w2q[bk * 32 + (l & 31)] : 0.f;
        pr2 += __shfl_xor(pr2, 32);
        pr2 += __shfl_xor(pr2, 16);
        pr2 += __shfl_xor(pr2,  8);
        pr2 += __shfl_xor(pr2,  4);
        pr2 += __shfl_xor(pr2,  2);
        pr2 += __shfl_xor(pr2,  1);

        if (l == 0) {
            const float o2   = pr2 + rintf(fc2_b[bk]);
            const float skip = o0v[15] * (float)(9600.0 / 8128.0);
            const float ps   = stm ? s_psqt[1] : s_psqt[0];
            const float po   = stm ? s_psqt[0] : s_psqt[1];
            out[b] = (0.5f * (ps - po) + o2 + skip) * 0.0625f;
        }
    }
}

// ---------------- fallback (no ws): fp32 block-per-position ----------------
__global__ __launch_bounds__(256) void nnue_fb(
    const int* __restrict__ w_feats, const int* __restrict__ w_offsets,
    const int* __restrict__ b_feats, const int* __restrict__ b_offsets,
    const int* __restrict__ stm_arr, const int* __restrict__ bucket_arr,
    const float* __restrict__ ft_weight, const float* __restrict__ ft_bias,
    const float* __restrict__ psqt_weight,
    const float* __restrict__ fc0_w, const float* __restrict__ fc0_b,
    const float* __restrict__ fc1_w, const float* __restrict__ fc1_b,
    const float* __restrict__ fc2_w, const float* __restrict__ fc2_b,
    float* __restrict__ out, int n_wf, int n_bf, int nb)
{
    const int b = blockIdx.x;
    const int t = threadIdx.x;
    const int l = t & 63;
    const int w = t >> 6;

    __shared__ int s_fw[NFEATS], s_fb[NFEATS];
    __shared__ __align__(16) float s_acc[2][1024];
    __shared__ __align__(16) float s_ft[1024];
    __shared__ float s_o0[16];
    __shared__ float s_slab[32];
    __shared__ float s_ac1[32];
    __shared__ float s_psqt[2];

    const int ws = w_offsets[b];
    const int we = (b + 1 < nb) ? w_offsets[b + 1] : n_wf;
    const int bs = b_offsets[b];
    const int be = (b + 1 < nb) ? b_offsets[b + 1] : n_bf;
    const int cw = min(we - ws, NFEATS);
    const int cb = min(be - bs, NFEATS);

    if (t < NFEATS) s_fw[t] = (t < cw) ? w_feats[ws + t] : 0;
    else if (t < 2 * NFEATS) {
        const int k = t - NFEATS;
        s_fb[k] = (k < cb) ? b_feats[bs + k] : 0;
    }
    __syncthreads();

    const int stm = stm_arr[b];
    const int bk  = bucket_arr[b];

    if (t < 64) {
        const int side = t >> 5;
        const int k = t & 31;
        const int cnt = side ? cb : cw;
        float v = 0.f;
        if (k < cnt) v = rintf(psqt_weight[(side ? s_fb[k] : s_fw[k]) * 8 + bk]);
        v += __shfl_down(v, 16, 32); v += __shfl_down(v, 8, 32);
        v += __shfl_down(v, 4, 32);  v += __shfl_down(v, 2, 32);
        v += __shfl_down(v, 1, 32);
        if (k == 0) s_psqt[side] = v;
    }

    const float4* ftw4 = reinterpret_cast<const float4*>(ft_weight);
    float4 aw = make_float4(0, 0, 0, 0), ab = make_float4(0, 0, 0, 0);
    for (int k = 0; k < cw; ++k) {
        const float4 v = ftw4[s_fw[k] * 256 + t];
        aw.x += rintf(v.x); aw.y += rintf(v.y);
        aw.z += rintf(v.z); aw.w += rintf(v.w);
    }
    for (int k = 0; k < cb; ++k) {
        const float4 u = ftw4[s_fb[k] * 256 + t];
        ab.x += rintf(u.x); ab.y += rintf(u.y);
        ab.z += rintf(u.z); ab.w += rintf(u.w);
    }
    const float4 bv = reinterpret_cast<const float4*>(ft_bias)[t];
    aw.x += q16f(bv.x); aw.y += q16f(bv.y); aw.z += q16f(bv.z); aw.w += q16f(bv.w);
    ab.x += q16f(bv.x); ab.y += q16f(bv.y); ab.z += q16f(bv.z); ab.w += q16f(bv.w);
    reinterpret_cast<float4*>(&s_acc[0][4 * t])[0] = aw;
    reinterpret_cast<float4*>(&s_acc[1][4 * t])[0] = ab;
    __syncthreads();

    {
        float4 lo, hi;
        if (t < 128) {
            const float* sp = s_acc[stm];
            lo = ((const float4*)sp)[t]; hi = ((const float4*)sp)[t + 128];
        } else {
            const float* sp = s_acc[1 - stm];
            lo = ((const float4*)sp)[t - 128]; hi = ((const float4*)sp)[t];
        }
        float4 r;
        r.x = clip127(lo.x) * clip127(hi.x) * 0.0078125f;
        r.y = clip127(lo.y) * clip127(hi.y) * 0.0078125f;
        r.z = clip127(lo.z) * clip127(hi.z) * 0.0078125f;
        r.w = clip127(lo.w) * clip127(hi.w) * 0.0078125f;
        ((float4*)s_ft)[t] = r;
    }
    __syncthreads();

    {
        const float4* ftf4 = (const float4*)s_ft;
        const float4 f0 = ftf4[l], f1 = ftf4[l + 64],
                     f2 = ftf4[l + 128], f3 = ftf4[l + 192];
        #pragma unroll
        for (int o = 0; o < 4; ++o) {
            const int orow = 4 * w + o;
            const float4* wr = (const float4*)fc0_w + ((size_t)bk * 16 + orow) * 256;
            const float4 w0 = q8f4(wr[l]), w1 = q8f4(wr[l + 64]),
                         w2 = q8f4(wr[l + 128]), w3 = q8f4(wr[l + 192]);
            float acc = f0.x * w0.x + f0.y * w0.y + f0.z * w0.z + f0.w * w0.w
                      + f1.x * w1.x + f1.y * w1.y + f1.z * w1.z + f1.w * w1.w
                      + f2.x * w2.x + f2.y * w2.y + f2.z * w2.z + f2.w * w2.w
                      + f3.x * w3.x + f3.y * w3.y + f3.z * w3.z + f3.w * w3.w;
            acc += __shfl_down(acc, 32); acc += __shfl_down(acc, 16);
            acc += __shfl_down(acc, 8);  acc += __shfl_down(acc, 4);
            acc += __shfl_down(acc, 2);  acc += __shfl_down(acc, 1);
            if (l == 0) s_o0[orow] = acc + rintf(fc0_b[bk * 16 + orow]);
        }
    }
    __syncthreads();

    if (t < 32) {
        float v;
        if (t < 15)      v = clip127(s_o0[t] * s_o0[t] * (1.f / 524288.f));
        else if (t < 30) v = clip127(s_o0[t - 15] * 0.015625f);
        else             v = 0.f;
        s_slab[t] = v;
    }
    __syncthreads();

    if (t < 32) {
        const float* w1 = fc1_w + (size_t)bk * 32 * 32 + t * 32;
        float acc = rintf(fc1_b[bk * 32 + t]);
        #pragma unroll
        for (int i = 0; i < 32; ++i) acc += s_slab[i] * q8f(w1[i]);
        s_ac1[t] = clip127(acc * 0.015625f);
    }
    __syncthreads();

    if (t == 0) {
        const float* w2 = fc2_w + (size_t)bk * 32;
        float acc = rintf(fc2_b[bk]);
        #pragma unroll
        for (int i = 0; i < 32; ++i) acc += s_ac1[i] * q8f(w2[i]);
        const float skip = s_o0[15] * (float)(9600.0 / 8128.0);
        const float ps = stm ? s_psqt[1] : s_psqt[0];
        const float po = stm ? s_psqt[0] : s_psqt[1];
        out[b] = (0.5f * (ps - po) + acc + skip) * 0.0625f;
    }
}

extern "C" void kernel_launch(void* const* d_in, const int* in_sizes, int n_in,
                              void* d_out, int out_size, void* d_ws, size_t ws_size,
                              hipStream_t stream) {
    const int*   w_feats   = (const int*)d_in[0];
    const int*   w_offsets = (const int*)d_in[1];
    const int*   b_feats   = (const int*)d_in[2];
    const int*   b_offsets = (const int*)d_in[3];
    const int*   stm       = (const int*)d_in[4];
    const int*   bucket    = (const int*)d_in[5];
    const float* ft_weight = (const float*)d_in[6];
    const float* ft_bias   = (const float*)d_in[7];
    const float* psqt_w    = (const float*)d_in[8];
    const float* fc0_w     = (const float*)d_in[9];
    const float* fc0_b     = (const float*)d_in[10];
    const float* fc1_w     = (const float*)d_in[11];
    const float* fc1_b     = (const float*)d_in[12];
    const float* fc2_w     = (const float*)d_in[13];
    const float* fc2_b     = (const float*)d_in[14];
    float*       out       = (float*)d_out;

    const int nb   = in_sizes[4];
    const int n_wf = in_sizes[0];
    const int n_bf = in_sizes[2];

    if (ws_size >= WS_NEED) {
        const int nthreads = TBL_N4 + FC0_N4 + FC1_N4 + FC2_N4;
        cvt_v5<<<(nthreads + 255) / 256, 256, 0, stream>>>(
            (const float4*)ft_weight, (const float4*)fc0_w,
            (const float4*)fc1_w, (const float4*)fc2_w, (char*)d_ws);

        const char*  tbl = (const char*)d_ws;
        const float* w0q = (const float*)((char*)d_ws + OFF_W0);
        const float* w1q = (const float*)((char*)d_ws + OFF_W1);
        const float* w2q = (const float*)((char*)d_ws + OFF_W2);

        nnue_v5<<<nb, 128, 0, stream>>>(
            w_feats, w_offsets, b_feats, b_offsets, stm, bucket,
            tbl, w0q, w1q, w2q, ft_bias, psqt_w, fc0_b, fc1_b, fc2_b,
            out, n_wf, n_bf, nb);
    } else {
        nnue_fb<<<nb, 256, 0, stream>>>(
            w_feats, w_offsets, b_feats, b_offsets, stm, bucket,
            ft_weight, ft_bias, psqt_w,
            fc0_w, fc0_b, fc1_w, fc1_b, fc2_w, fc2_b,
            out, n_wf, n_bf, nb);
    }
}